// Round 1
// baseline (1164.528 us; speedup 1.0000x reference)
//
#include <hip/hip_runtime.h>

#define N_EMB 200000
#define K_C   512
#define D_DIM 128

// d_ws layout:
//   [0,    4096): unsigned long long pack[512]   (d2_bits<<32 | n), atomicMin target
//   [4096, 4100): float loss accumulator
//   [4160, 6208): float c2[512]

__global__ void init_kernel(const float* __restrict__ centers,
                            unsigned long long* __restrict__ pack,
                            float* __restrict__ c2,
                            float* __restrict__ loss) {
    int k = blockIdx.x * blockDim.x + threadIdx.x;
    if (k < K_C) {
        const float4* c = reinterpret_cast<const float4*>(centers + k * D_DIM);
        float s = 0.f;
#pragma unroll
        for (int i = 0; i < D_DIM / 4; ++i) {
            float4 v = c[i];
            s += v.x * v.x + v.y * v.y + v.z * v.z + v.w * v.w;
        }
        c2[k] = s;
        pack[k] = 0xFFFFFFFFFFFFFFFFULL;
        if (k == 0) *loss = 0.f;
    }
}

__launch_bounds__(256)
__global__ void cluster_main(const float* __restrict__ embs,
                             const float* __restrict__ centers,
                             const float* __restrict__ c2,
                             unsigned long long* __restrict__ pack,
                             float* __restrict__ loss) {
    __shared__ unsigned long long lds_best[4][K_C];  // 16 KB

    const int tid  = threadIdx.x;
    const int wave = tid >> 6;
    const int lane = tid & 63;
    const int n    = blockIdx.x * 256 + tid;
    const bool active = (n < N_EMB);
    const int wave_n_base = blockIdx.x * 256 + wave * 64;

    // Load this thread's embedding row into registers.
    float e[D_DIM];
    if (active) {
        const float4* ep = reinterpret_cast<const float4*>(embs + (size_t)n * D_DIM);
#pragma unroll
        for (int i = 0; i < D_DIM / 4; ++i) {
            float4 v = ep[i];
            e[4 * i + 0] = v.x; e[4 * i + 1] = v.y;
            e[4 * i + 2] = v.z; e[4 * i + 3] = v.w;
        }
    } else {
#pragma unroll
        for (int i = 0; i < D_DIM; ++i) e[i] = 0.f;
    }

    float x2 = 0.f;
#pragma unroll
    for (int i = 0; i < D_DIM; ++i) x2 = fmaf(e[i], e[i], x2);

    float minD2 = 3.4e38f;

    for (int k = 0; k < K_C; ++k) {
        const float* __restrict__ ck = centers + k * D_DIM;  // wave-uniform -> s_load
        float a0 = 0.f, a1 = 0.f, a2 = 0.f, a3 = 0.f;
#pragma unroll
        for (int d = 0; d < D_DIM; d += 4) {
            a0 = fmaf(e[d + 0], ck[d + 0], a0);
            a1 = fmaf(e[d + 1], ck[d + 1], a1);
            a2 = fmaf(e[d + 2], ck[d + 2], a2);
            a3 = fmaf(e[d + 3], ck[d + 3], a3);
        }
        float dot = (a0 + a1) + (a2 + a3);
        float d2 = x2 + c2[k] - 2.f * dot;
        d2 = fmaxf(d2, 1e-12f);                 // matches reference clamp
        float d2m = active ? d2 : 3.4e38f;
        minD2 = fminf(minD2, d2m);

        // Wave-level argmin: min-tree + first-lane-of-min (ties -> lowest n).
        float m = d2m;
#pragma unroll
        for (int off = 1; off < 64; off <<= 1)
            m = fminf(m, __shfl_xor(m, off));
        unsigned long long msk = __ballot(d2m == m);
        int winner = __ffsll(msk) - 1;
        if (lane == 0) {
            unsigned fb = __float_as_uint(m);   // m >= 0 -> bit pattern order-preserving
            lds_best[wave][k] =
                ((unsigned long long)fb << 32) | (unsigned)(wave_n_base + winner);
        }
    }
    __syncthreads();

    // Block combine (4 waves) -> one atomicMin per k per block.
    for (int kk = tid; kk < K_C; kk += 256) {
        unsigned long long b = lds_best[0][kk];
        unsigned long long t1 = lds_best[1][kk]; if (t1 < b) b = t1;
        unsigned long long t2 = lds_best[2][kk]; if (t2 < b) b = t2;
        unsigned long long t3 = lds_best[3][kk]; if (t3 < b) b = t3;
        atomicMin(&pack[kk], b);
    }

    // Loss: sum of sqrt(min d2) over this wave, one atomic per wave.
    float l = active ? sqrtf(minD2) : 0.f;
#pragma unroll
    for (int off = 1; off < 64; off <<= 1)
        l += __shfl_xor(l, off);
    if (lane == 0) atomicAdd(loss, l);
}

__global__ void finalize_kernel(const float* __restrict__ centers,
                                const unsigned long long* __restrict__ pack,
                                const float* __restrict__ loss,
                                float* __restrict__ out) {
    int tid = blockIdx.x * blockDim.x + threadIdx.x;  // 64 x 256 = 16384
    // Output 0: centers pass-through (65536 floats = 16384 float4).
    const float4* src = reinterpret_cast<const float4*>(centers);
    float4* dst = reinterpret_cast<float4*>(out);
    if (tid < 16384) dst[tid] = src[tid];
    // Output 1: rep_ids as float.
    if (tid < K_C) {
        unsigned long long p = pack[tid];
        out[65536 + tid] = (float)(unsigned)(p & 0xFFFFFFFFu);
    }
    // Output 2: loss scalar.
    if (tid == 0) out[65536 + K_C] = *loss;
}

extern "C" void kernel_launch(void* const* d_in, const int* in_sizes, int n_in,
                              void* d_out, int out_size, void* d_ws, size_t ws_size,
                              hipStream_t stream) {
    const float* embs    = (const float*)d_in[0];
    const float* centers = (const float*)d_in[1];
    float* out = (float*)d_out;

    unsigned long long* pack = (unsigned long long*)d_ws;
    float* lossp = (float*)((char*)d_ws + 4096);
    float* c2    = (float*)((char*)d_ws + 4160);

    init_kernel<<<2, 256, 0, stream>>>(centers, pack, c2, lossp);

    int nblocks = (N_EMB + 255) / 256;  // 782
    cluster_main<<<nblocks, 256, 0, stream>>>(embs, centers, c2, pack, lossp);

    finalize_kernel<<<64, 256, 0, stream>>>(centers, pack, lossp, out);
}

// Round 2
// 378.711 us; speedup vs baseline: 3.0750x; 3.0750x over previous
//
#include <hip/hip_runtime.h>
#include <hip/hip_bf16.h>

typedef __attribute__((ext_vector_type(8)))  short          bf16x8;
typedef __attribute__((ext_vector_type(16))) float          f32x16;
typedef __attribute__((ext_vector_type(8)))  unsigned short u16x8;

#define N_EMB 200000
#define K_C   512
#define D_DIM 128
#define NTILES_TOT 6250      // 200000 / 32, exact
#define TILES_PER_BLK 8
#define NGRPS 782            // ceil(6250/8); last group has 2 tiles
#define LDS_STRIDE 304       // bytes/row = 19 x 16B blocks (16 data + 2 extra + 1 pad)
#define LDS_LO_OFF 9728      // 32*304
#define LDS_MIN_OFF 19456

// ws layout: pack u64[512] @0 ; minbits u32[200000] @4096 ; loss f32 @804352

__device__ __forceinline__ unsigned short bf16_bits(float x) {
    __hip_bfloat16 h = __float2bfloat16(x);
    return *reinterpret_cast<unsigned short*>(&h);
}
__device__ __forceinline__ float bf16_val(unsigned short b) {
    __hip_bfloat16 h;
    *reinterpret_cast<unsigned short*>(&h) = b;
    return __bfloat162float(h);
}

__global__ void init_kernel(unsigned long long* __restrict__ pack,
                            unsigned* __restrict__ minbits,
                            float* __restrict__ loss) {
    int gid = blockIdx.x * 256 + threadIdx.x;
    if (gid < K_C) pack[gid] = 0xFFFFFFFFFFFFFFFFULL;
    if (gid < N_EMB) minbits[gid] = 0xFFFFFFFFu;
    if (gid == 0) *loss = 0.f;
}

__launch_bounds__(512, 2)
__global__ void cluster_mfma(const float* __restrict__ embs,
                             const float* __restrict__ centers,
                             unsigned long long* __restrict__ pack,
                             unsigned* __restrict__ minbits) {
    __shared__ __align__(16) char lds[20480];
    unsigned* minarr = reinterpret_cast<unsigned*>(lds + LDS_MIN_OFF);

    const int t     = threadIdx.x;
    const int w     = t >> 6;          // wave 0..7
    const int l     = t & 63;          // lane
    const int col   = l & 31;          // MFMA col (= n within tile; = A k-row within wave)
    const int half  = l >> 5;          // lane group (k-slot half)
    const int kside = blockIdx.x & 1;  // which 256 centers
    const int ngrp  = blockIdx.x >> 1; // which 256-n window
    const int kbase = kside * 256 + w * 32;
    const int myk   = kbase + col;     // this lane's A row (a center index)

    // staging role
    const int srow   = t >> 4;         // 0..31 (n-row within tile)
    const int schunk = t & 15;         // 8-elem d-chunk

    const unsigned short ONE = 0x3F80; // bf16 1.0

    // ---------------- A prep: centers row -> (-2c) hi/lo bf16 frags + c2 fold ----------------
    bf16x8 a_hi[9], a_lo[9];
    float c2p = 0.f;
    {
        const float* crow = centers + myk * D_DIM + 8 * half;
#pragma unroll
        for (int s = 0; s < 8; ++s) {
            float4 v0 = *reinterpret_cast<const float4*>(crow + 16 * s);
            float4 v1 = *reinterpret_cast<const float4*>(crow + 16 * s + 4);
            float v[8] = {v0.x, v0.y, v0.z, v0.w, v1.x, v1.y, v1.z, v1.w};
            bf16x8 hv, lv;
#pragma unroll
            for (int i = 0; i < 8; ++i) {
                c2p = fmaf(v[i], v[i], c2p);
                float x = -2.f * v[i];
                unsigned short hb = bf16_bits(x);
                float hf = bf16_val(hb);
                unsigned short lb = bf16_bits(x - hf);
                hv[i] = (short)hb;
                lv[i] = (short)lb;
            }
            a_hi[s] = hv;
            a_lo[s] = lv;
        }
        float c2 = c2p + __shfl_xor(c2p, 32);   // full-row sum (row split across lane halves)
        bf16x8 h8, l8;
#pragma unroll
        for (int i = 0; i < 8; ++i) { h8[i] = 0; l8[i] = 0; }
        if (half == 0) {
            unsigned short c2h = bf16_bits(c2);
            float c2hf = bf16_val(c2h);
            unsigned short c2l = bf16_bits(c2 - c2hf);
            float c2lf = bf16_val(c2l);
            unsigned short e2c = bf16_bits(c2 - c2hf - c2lf);
            h8[0] = (short)c2h; h8[1] = (short)ONE; h8[2] = (short)e2c;
            l8[0] = (short)c2l; l8[3] = (short)ONE;
        }
        a_hi[8] = h8;
        a_lo[8] = l8;
    }

    // per-(lane,reg) running best over all n this block sees, for 16 fixed k's
    float    best_d[16];
    unsigned best_n[16];
#pragma unroll
    for (int r = 0; r < 16; ++r) { best_d[r] = 3.4e38f; best_n[r] = 0u; }

    if (t < 256) minarr[t] = 0xFFFFFFFFu;

    const int tstart = ngrp * TILES_PER_BLK;
    const int tcnt   = (NTILES_TOT - tstart < TILES_PER_BLK) ? (NTILES_TOT - tstart)
                                                             : TILES_PER_BLK;

    for (int tl = 0; tl < tcnt; ++tl) {
        const int n0 = (tstart + tl) * 32;

        // ---------------- stage B tile: 32 n x 128 d -> hi/lo bf16 (+x2 fold slots) ----------------
        {
            const float* erow = embs + (size_t)(n0 + srow) * D_DIM + schunk * 8;
            float4 u0 = *reinterpret_cast<const float4*>(erow);
            float4 u1 = *reinterpret_cast<const float4*>(erow + 4);
            float v[8] = {u0.x, u0.y, u0.z, u0.w, u1.x, u1.y, u1.z, u1.w};
            float x2p = 0.f;
            u16x8 hv, lv;
#pragma unroll
            for (int i = 0; i < 8; ++i) {
                x2p = fmaf(v[i], v[i], x2p);
                unsigned short hb = bf16_bits(v[i]);
                float hf = bf16_val(hb);
                unsigned short lb = bf16_bits(v[i] - hf);
                hv[i] = hb;
                lv[i] = lb;
            }
            const int blk = schunk ^ (srow & 15);
            *reinterpret_cast<u16x8*>(lds + srow * LDS_STRIDE + (blk << 4)) = hv;
            *reinterpret_cast<u16x8*>(lds + LDS_LO_OFF + srow * LDS_STRIDE + (blk << 4)) = lv;
            // x2 = row sum across the 16 threads of this row (lanes stay in 16-groups)
            float x2 = x2p;
#pragma unroll
            for (int off = 1; off < 16; off <<= 1) x2 += __shfl_xor(x2, off);
            if (schunk == 0) {
                unsigned short x2h = bf16_bits(x2);
                float x2hf = bf16_val(x2h);
                unsigned short x2l = bf16_bits(x2 - x2hf);
                float x2lf = bf16_val(x2l);
                unsigned short e2x = bf16_bits(x2 - x2hf - x2lf);
                u16x8 he, le, z;
#pragma unroll
                for (int i = 0; i < 8; ++i) { he[i] = 0; le[i] = 0; z[i] = 0; }
                he[0] = ONE; he[1] = x2h; he[2] = ONE; he[3] = e2x;
                le[1] = x2l;
                char* rowp = lds + srow * LDS_STRIDE;
                *reinterpret_cast<u16x8*>(rowp + (16 << 4)) = he;                    // d 128..135 hi
                *reinterpret_cast<u16x8*>(rowp + (17 << 4)) = z;                     // d 136..143 hi
                *reinterpret_cast<u16x8*>(rowp + LDS_LO_OFF + (16 << 4)) = le;       // d 128..135 lo
                *reinterpret_cast<u16x8*>(rowp + LDS_LO_OFF + (17 << 4)) = z;        // d 136..143 lo
            }
        }
        __syncthreads();

        // ---------------- MFMA: 32k x 32n, d2 lands directly in acc ----------------
        f32x16 acc;
#pragma unroll
        for (int r = 0; r < 16; ++r) acc[r] = 0.f;

#pragma unroll
        for (int s = 0; s < 9; ++s) {
            const int dblk = (s < 8) ? ((2 * s + half) ^ (col & 15)) : (16 + half);
            bf16x8 bh = *reinterpret_cast<bf16x8*>(lds + col * LDS_STRIDE + (dblk << 4));
            bf16x8 bl = *reinterpret_cast<bf16x8*>(lds + LDS_LO_OFF + col * LDS_STRIDE + (dblk << 4));
            acc = __builtin_amdgcn_mfma_f32_32x32x16_bf16(a_hi[s], bh, acc, 0, 0, 0);
            acc = __builtin_amdgcn_mfma_f32_32x32x16_bf16(a_hi[s], bl, acc, 0, 0, 0);
            acc = __builtin_amdgcn_mfma_f32_32x32x16_bf16(a_lo[s], bh, acc, 0, 0, 0);
        }

        // ---------------- epilogue ----------------
        // loss path: min over this wave's 32 k for my n-col
        float m = acc[0];
#pragma unroll
        for (int r = 1; r < 16; ++r) m = fminf(m, acc[r]);
        m = fminf(m, __shfl_xor(m, 32));
        if (l < 32) atomicMin(&minarr[tl * 32 + col], __float_as_uint(m));

        // rep path: per-reg running best (k fixed per (lane,reg), candidate n = n0+col)
        const unsigned ng = (unsigned)(n0 + col);
#pragma unroll
        for (int r = 0; r < 16; ++r) {
            float d2 = acc[r];
            bool better = d2 < best_d[r];
            best_d[r] = better ? d2 : best_d[r];
            best_n[r] = better ? ng : best_n[r];
        }
        __syncthreads();
    }

    // ---------------- block finish ----------------
    // per-n min -> global combine across the 2 k-side blocks
    if (t < tcnt * 32) atomicMin(&minbits[ngrp * 256 + t], minarr[t]);

    // rep: cross-lane (32 cols of each half) lexicographic argmin, then global pack
#pragma unroll
    for (int r = 0; r < 16; ++r) {
        float d = best_d[r];
        unsigned n = best_n[r];
        for (int off = 16; off >= 1; off >>= 1) {
            float od = __shfl_xor(d, off);
            unsigned on = __shfl_xor(n, off);
            bool take = (od < d) || (od == d && on < n);
            d = take ? od : d;
            n = take ? on : n;
        }
        if (col == 0) {
            int k = kbase + (r & 3) + 8 * (r >> 2) + 4 * half;
            unsigned long long p =
                ((unsigned long long)__float_as_uint(d) << 32) | (unsigned long long)n;
            atomicMin(&pack[k], p);
        }
    }
}

__global__ void finalize1(const unsigned* __restrict__ minbits,
                          float* __restrict__ loss) {
    int n = blockIdx.x * 256 + threadIdx.x;
    float s = 0.f;
    if (n < N_EMB) s = sqrtf(fmaxf(__uint_as_float(minbits[n]), 1e-12f));
#pragma unroll
    for (int off = 1; off < 64; off <<= 1) s += __shfl_xor(s, off);
    if ((threadIdx.x & 63) == 0) atomicAdd(loss, s);
}

__global__ void finalize2(const float* __restrict__ centers,
                          const unsigned long long* __restrict__ pack,
                          const float* __restrict__ loss,
                          float* __restrict__ out) {
    int gid = blockIdx.x * 256 + threadIdx.x;   // 64*256 = 16384
    const float4* src = reinterpret_cast<const float4*>(centers);
    float4* dst = reinterpret_cast<float4*>(out);
    if (gid < 16384) dst[gid] = src[gid];
    if (gid < K_C) out[65536 + gid] = (float)(unsigned)(pack[gid] & 0xFFFFFFFFu);
    if (gid == 0) out[65536 + K_C] = *loss;
}

extern "C" void kernel_launch(void* const* d_in, const int* in_sizes, int n_in,
                              void* d_out, int out_size, void* d_ws, size_t ws_size,
                              hipStream_t stream) {
    const float* embs    = (const float*)d_in[0];
    const float* centers = (const float*)d_in[1];
    float* out = (float*)d_out;

    unsigned long long* pack = (unsigned long long*)d_ws;
    unsigned* minbits = (unsigned*)((char*)d_ws + 4096);
    float* lossp = (float*)((char*)d_ws + 804352);

    init_kernel<<<NGRPS, 256, 0, stream>>>(pack, minbits, lossp);
    cluster_mfma<<<NGRPS * 2, 512, 0, stream>>>(embs, centers, pack, minbits);
    finalize1<<<NGRPS, 256, 0, stream>>>(minbits, lossp);
    finalize2<<<64, 256, 0, stream>>>(centers, pack, lossp, out);
}

// Round 4
// 296.884 us; speedup vs baseline: 3.9225x; 1.2756x over previous
//
#include <hip/hip_runtime.h>
#include <hip/hip_bf16.h>

typedef __attribute__((ext_vector_type(8)))  short          bf16x8;
typedef __attribute__((ext_vector_type(16))) float          f32x16;
typedef __attribute__((ext_vector_type(8)))  unsigned short u16x8;

#define N_EMB 200000
#define K_C   512
#define D_DIM 128
#define TPB   10            // 32-n tiles per block; 6250 tiles = 625 groups x 10, exact
#define NGRPS 625
#define AROW  144           // split-A row: 128 data + 16 fold elems
#define BUFB  18432         // per LDS buffer: hi 9216 + lo 9216
#define LOOFF 9216
#define MINOFF (2*BUFB)     // 36864

// ws layout (bytes):
//   0        pack u64[512]            (4096)
//   4096     hiA u16[512*144]         (147456)  ends 151552
//   151552   loA u16[512*144]         (147456)  ends 299008
//   299008   minA u32[200000]         (800000)  ends 1099008
//   1099008  minB u32[200000]         (800000)  ends 1899008
//   1899008  loss f32

__device__ __forceinline__ unsigned short bf16_bits(float x) {
    __hip_bfloat16 h = __float2bfloat16(x);
    return *reinterpret_cast<unsigned short*>(&h);
}
__device__ __forceinline__ float bf16_val(unsigned short b) {
    unsigned u = (unsigned)b << 16;
    return __uint_as_float(u);
}

// LDS 16B-block index: group-major, XOR swizzle for conflict-free r/w.
__device__ __forceinline__ int BLK(int g, int n) { return (g << 5) | (n ^ (g & 7)); }

__global__ void init_kernel(const float* __restrict__ centers,
                            unsigned short* __restrict__ hiA,
                            unsigned short* __restrict__ loA,
                            unsigned long long* __restrict__ pack,
                            float* __restrict__ loss) {
    const int t = threadIdx.x, w = t >> 6, l = t & 63;
    const int k = blockIdx.x * 8 + w;            // 64 blocks x 8 waves = 512 rows
    const float2 c = *reinterpret_cast<const float2*>(centers + k * D_DIM + 2 * l);
    float c2 = c.x * c.x + c.y * c.y;
#pragma unroll
    for (int off = 1; off < 64; off <<= 1) c2 += __shfl_xor(c2, off);

    float v0 = -2.f * c.x, v1 = -2.f * c.y;
    unsigned short h0 = bf16_bits(v0); unsigned short l0 = bf16_bits(v0 - bf16_val(h0));
    unsigned short h1 = bf16_bits(v1); unsigned short l1 = bf16_bits(v1 - bf16_val(h1));
    *reinterpret_cast<ushort2*>(hiA + k * AROW + 2 * l) = make_ushort2(h0, h1);
    *reinterpret_cast<ushort2*>(loA + k * AROW + 2 * l) = make_ushort2(l0, l1);

    if (l == 0) {   // hi fold row: {c2h, 1, e2c, 0...}, then zeros
        unsigned short c2h = bf16_bits(c2);
        float c2hf = bf16_val(c2h);
        unsigned short c2l = bf16_bits(c2 - c2hf);
        float c2lf = bf16_val(c2l);
        unsigned short e2c = bf16_bits(c2 - c2hf - c2lf);
        u16x8 a, z;
#pragma unroll
        for (int i = 0; i < 8; ++i) { a[i] = 0; z[i] = 0; }
        a[0] = c2h; a[1] = 0x3F80; a[2] = e2c;
        *reinterpret_cast<u16x8*>(hiA + k * AROW + 128) = a;
        *reinterpret_cast<u16x8*>(hiA + k * AROW + 136) = z;
    }
    if (l == 1) {   // lo fold row: {c2l, 0, 0, 1, 0...}, then zeros
        unsigned short c2h = bf16_bits(c2);
        unsigned short c2l = bf16_bits(c2 - bf16_val(c2h));
        u16x8 a, z;
#pragma unroll
        for (int i = 0; i < 8; ++i) { a[i] = 0; z[i] = 0; }
        a[0] = c2l; a[3] = 0x3F80;
        *reinterpret_cast<u16x8*>(loA + k * AROW + 128) = a;
        *reinterpret_cast<u16x8*>(loA + k * AROW + 136) = z;
    }
    if (l == 2) pack[k] = 0xFFFFFFFFFFFFFFFFULL;
    if (blockIdx.x == 0 && t == 0) *loss = 0.f;
}

__launch_bounds__(512, 2)
__global__ void cluster_mfma(const float* __restrict__ embs,
                             const unsigned short* __restrict__ hiA,
                             const unsigned short* __restrict__ loA,
                             unsigned long long* __restrict__ pack,
                             unsigned* __restrict__ minA,
                             unsigned* __restrict__ minB) {
    __shared__ __align__(16) char lds_c[2 * BUFB + TPB * 32 * 4];
    unsigned* minarr = reinterpret_cast<unsigned*>(lds_c + MINOFF);

    const int t = threadIdx.x, w = t >> 6, l = t & 63;
    const int col = l & 31, half = l >> 5;
    const int kside = blockIdx.x & 1, ngrp = blockIdx.x >> 1;
    const int kbase = kside * 256 + w * 32;
    const int myk = kbase + col;
    const int srow = t >> 4, schunk = t & 15;
    const int tbase = ngrp * TPB;

    // ---- A fragments from precomputed split (9 hi + 9 lo, incl. fold) ----
    bf16x8 a_hi[9], a_lo[9];
    {
        const unsigned short* hrow = hiA + myk * AROW + 8 * half;
        const unsigned short* lrow = loA + myk * AROW + 8 * half;
#pragma unroll
        for (int s = 0; s < 9; ++s) {
            a_hi[s] = *reinterpret_cast<const bf16x8*>(hrow + 16 * s);
            a_lo[s] = *reinterpret_cast<const bf16x8*>(lrow + 16 * s);
        }
    }

    float    best_d[16];
    unsigned best_n[16];
#pragma unroll
    for (int r = 0; r < 16; ++r) { best_d[r] = 3.4e38f; best_n[r] = 0u; }

    if (t < TPB * 32) minarr[t] = 0xFFFFFFFFu;

    // preload tile 0
    float vcur[8];
    {
        const float* erow = embs + (tbase * 32 + srow) * D_DIM + schunk * 8;
        float4 u0 = *reinterpret_cast<const float4*>(erow);
        float4 u1 = *reinterpret_cast<const float4*>(erow + 4);
        vcur[0] = u0.x; vcur[1] = u0.y; vcur[2] = u0.z; vcur[3] = u0.w;
        vcur[4] = u1.x; vcur[5] = u1.y; vcur[6] = u1.z; vcur[7] = u1.w;
    }

    for (int tl = 0; tl < TPB; ++tl) {
        char* buf = lds_c + (tl & 1) * BUFB;

        // ---- prefetch next tile into regs (overlaps convert + MFMA) ----
        float vnx[8];
        {
            const int tn = (tl < TPB - 1) ? tl + 1 : tl;   // clamped dup on last iter
            const float* erow = embs + ((tbase + tn) * 32 + srow) * D_DIM + schunk * 8;
            float4 u0 = *reinterpret_cast<const float4*>(erow);
            float4 u1 = *reinterpret_cast<const float4*>(erow + 4);
            vnx[0] = u0.x; vnx[1] = u0.y; vnx[2] = u0.z; vnx[3] = u0.w;
            vnx[4] = u1.x; vnx[5] = u1.y; vnx[6] = u1.z; vnx[7] = u1.w;
        }

        // ---- convert current tile -> LDS (hi/lo) + x2 fold rows ----
        {
            float x2p = 0.f;
            u16x8 hv, lv;
#pragma unroll
            for (int i = 0; i < 8; ++i) {
                float v = vcur[i];
                x2p = fmaf(v, v, x2p);
                unsigned short hb = bf16_bits(v);
                unsigned short lb = bf16_bits(v - bf16_val(hb));
                hv[i] = hb; lv[i] = lb;
            }
            const int wb = BLK(schunk, srow);
            *reinterpret_cast<u16x8*>(buf + (wb << 4)) = hv;
            *reinterpret_cast<u16x8*>(buf + LOOFF + (wb << 4)) = lv;
            float x2 = x2p;
#pragma unroll
            for (int off = 1; off < 16; off <<= 1) x2 += __shfl_xor(x2, off);
            if (schunk == 0) {
                unsigned short x2h = bf16_bits(x2);
                float x2hf = bf16_val(x2h);
                unsigned short x2l = bf16_bits(x2 - x2hf);
                float x2lf = bf16_val(x2l);
                unsigned short e2x = bf16_bits(x2 - x2hf - x2lf);
                u16x8 he, le, z;
#pragma unroll
                for (int i = 0; i < 8; ++i) { he[i] = 0; le[i] = 0; z[i] = 0; }
                he[0] = 0x3F80; he[1] = x2h; he[2] = 0x3F80; he[3] = e2x;
                le[1] = x2l;
                const int b16 = BLK(16, srow), b17 = BLK(17, srow);
                *reinterpret_cast<u16x8*>(buf + (b16 << 4)) = he;
                *reinterpret_cast<u16x8*>(buf + (b17 << 4)) = z;
                *reinterpret_cast<u16x8*>(buf + LOOFF + (b16 << 4)) = le;
                *reinterpret_cast<u16x8*>(buf + LOOFF + (b17 << 4)) = z;
            }
        }
        __syncthreads();   // single barrier per tile (double-buffer proof in header)

        // ---- MFMA: 9 steps x 3 passes; acc IS d2 (x2+c2 folded) ----
        f32x16 acc;
#pragma unroll
        for (int r = 0; r < 16; ++r) acc[r] = 0.f;
#pragma unroll
        for (int s = 0; s < 9; ++s) {
            const int gg = (s < 8) ? (2 * s + half) : (16 + half);
            const char* pb = buf + (BLK(gg, col) << 4);
            bf16x8 bh = *reinterpret_cast<const bf16x8*>(pb);
            bf16x8 bl = *reinterpret_cast<const bf16x8*>(pb + LOOFF);
            acc = __builtin_amdgcn_mfma_f32_32x32x16_bf16(a_hi[s], bh, acc, 0, 0, 0);
            acc = __builtin_amdgcn_mfma_f32_32x32x16_bf16(a_hi[s], bl, acc, 0, 0, 0);
            acc = __builtin_amdgcn_mfma_f32_32x32x16_bf16(a_lo[s], bh, acc, 0, 0, 0);
        }

        // ---- epilogue: loss min (per n) + rep running best (per k) ----
        float m = acc[0];
#pragma unroll
        for (int r = 1; r < 16; ++r) m = fminf(m, acc[r]);
        m = fminf(m, __shfl_xor(m, 32));
        if (l < 32) atomicMin(&minarr[tl * 32 + col], __float_as_uint(m));

        const unsigned ng = (unsigned)((tbase + tl) * 32 + col);
#pragma unroll
        for (int r = 0; r < 16; ++r) {
            bool better = acc[r] < best_d[r];
            best_d[r] = better ? acc[r] : best_d[r];
            best_n[r] = better ? ng : best_n[r];
        }

#pragma unroll
        for (int i = 0; i < 8; ++i) vcur[i] = vnx[i];
    }
    __syncthreads();

    // ---- per-n mins: plain store per kside (no global atomics) ----
    if (t < TPB * 32) {
        unsigned* dst = kside ? minB : minA;
        dst[ngrp * (TPB * 32) + t] = minarr[t];
    }

    // ---- rep: cross-lane lexicographic argmin, then global packed atomicMin ----
#pragma unroll
    for (int r = 0; r < 16; ++r) {
        float d = best_d[r];
        unsigned n = best_n[r];
        for (int off = 16; off >= 1; off >>= 1) {
            float od = __shfl_xor(d, off);
            unsigned on = __shfl_xor(n, off);
            bool take = (od < d) || (od == d && on < n);
            d = take ? od : d;
            n = take ? on : n;
        }
        if (col == 0) {
            int k = kbase + (r & 3) + 8 * (r >> 2) + 4 * half;
            unsigned long long p =
                ((unsigned long long)__float_as_uint(d) << 32) | (unsigned long long)n;
            atomicMin(&pack[k], p);
        }
    }
}

__global__ void finalize1(const float* __restrict__ centers,
                          const unsigned long long* __restrict__ pack,
                          const unsigned* __restrict__ minA,
                          const unsigned* __restrict__ minB,
                          float* __restrict__ loss,
                          float* __restrict__ out) {
    const int gid = blockIdx.x * 512 + threadIdx.x;
    if (gid < 16384)
        reinterpret_cast<float4*>(out)[gid] =
            reinterpret_cast<const float4*>(centers)[gid];
    if (gid < K_C)
        out[65536 + gid] = (float)(unsigned)(pack[gid] & 0xFFFFFFFFu);
    float s = 0.f;
    if (gid < N_EMB) {
        float m = fminf(__uint_as_float(minA[gid]), __uint_as_float(minB[gid]));
        s = sqrtf(fmaxf(m, 1e-12f));
    }
#pragma unroll
    for (int off = 1; off < 64; off <<= 1) s += __shfl_xor(s, off);
    if ((threadIdx.x & 63) == 0) atomicAdd(loss, s);
}

__global__ void finalize2(const float* __restrict__ loss, float* __restrict__ out) {
    if (threadIdx.x == 0) out[65536 + K_C] = *loss;
}

extern "C" void kernel_launch(void* const* d_in, const int* in_sizes, int n_in,
                              void* d_out, int out_size, void* d_ws, size_t ws_size,
                              hipStream_t stream) {
    const float* embs    = (const float*)d_in[0];
    const float* centers = (const float*)d_in[1];
    float* out = (float*)d_out;

    unsigned long long* pack = (unsigned long long*)d_ws;
    unsigned short* hiA = (unsigned short*)((char*)d_ws + 4096);
    unsigned short* loA = (unsigned short*)((char*)d_ws + 151552);
    unsigned* minA = (unsigned*)((char*)d_ws + 299008);
    unsigned* minB = (unsigned*)((char*)d_ws + 1099008);
    float* lossp = (float*)((char*)d_ws + 1899008);

    init_kernel<<<64, 512, 0, stream>>>(centers, hiA, loA, pack, lossp);
    cluster_mfma<<<NGRPS * 2, 512, 0, stream>>>(embs, hiA, loA, pack, minA, minB);
    finalize1<<<391, 512, 0, stream>>>(centers, pack, minA, minB, lossp, out);
    finalize2<<<1, 64, 0, stream>>>(lossp, out);
}

// Round 5
// 257.419 us; speedup vs baseline: 4.5239x; 1.1533x over previous
//
#include <hip/hip_runtime.h>
#include <hip/hip_bf16.h>

typedef __attribute__((ext_vector_type(8)))  short          bf16x8;
typedef __attribute__((ext_vector_type(16))) float          f32x16;
typedef __attribute__((ext_vector_type(8)))  unsigned short u16x8;

#define N_EMB 200000
#define K_C   512
#define D_DIM 128
#define TPB   10            // 32-n tiles per block; 6250 tiles = 625 groups x 10, exact
#define NGRPS 625
#define AROW  144           // split-A row: 128 data + 16 fold elems
#define BUFB  18432         // per LDS buffer: hi 9216 + lo 9216
#define LOOFF 9216
#define MINOFF (2*BUFB)     // 36864

// ws layout (bytes):
//   0        pack u64[512]            (4096)
//   4096     hiA u16[512*144]         (147456)  ends 151552
//   151552   loA u16[512*144]         (147456)  ends 299008
//   299008   minA u32[200000]         (800000)  ends 1099008
//   1099008  minB u32[200000]         (800000)  ends 1899008
//   1899008  lossPartial f32[391]     (1564)

__device__ __forceinline__ unsigned short bf16_bits(float x) {
    __hip_bfloat16 h = __float2bfloat16(x);
    return *reinterpret_cast<unsigned short*>(&h);
}
__device__ __forceinline__ float bf16_val(unsigned short b) {
    unsigned u = (unsigned)b << 16;
    return __uint_as_float(u);
}

// LDS 16B-block index: group-major, XOR swizzle for conflict-free r/w (r4: 0 conflicts).
__device__ __forceinline__ int BLK(int g, int n) { return (g << 5) | (n ^ (g & 7)); }

__global__ void init_kernel(const float* __restrict__ centers,
                            unsigned short* __restrict__ hiA,
                            unsigned short* __restrict__ loA,
                            unsigned long long* __restrict__ pack) {
    const int t = threadIdx.x, w = t >> 6, l = t & 63;
    const int k = blockIdx.x * 8 + w;            // 64 blocks x 8 waves = 512 rows
    const float2 c = *reinterpret_cast<const float2*>(centers + k * D_DIM + 2 * l);
    float c2 = c.x * c.x + c.y * c.y;
#pragma unroll
    for (int off = 1; off < 64; off <<= 1) c2 += __shfl_xor(c2, off);

    float v0 = -2.f * c.x, v1 = -2.f * c.y;
    unsigned short h0 = bf16_bits(v0); unsigned short l0 = bf16_bits(v0 - bf16_val(h0));
    unsigned short h1 = bf16_bits(v1); unsigned short l1 = bf16_bits(v1 - bf16_val(h1));
    *reinterpret_cast<ushort2*>(hiA + k * AROW + 2 * l) = make_ushort2(h0, h1);
    *reinterpret_cast<ushort2*>(loA + k * AROW + 2 * l) = make_ushort2(l0, l1);

    if (l == 0) {   // hi fold row: {c2h, 1, e2c, 0...}
        unsigned short c2h = bf16_bits(c2);
        float c2hf = bf16_val(c2h);
        unsigned short c2l = bf16_bits(c2 - c2hf);
        float c2lf = bf16_val(c2l);
        unsigned short e2c = bf16_bits(c2 - c2hf - c2lf);
        u16x8 a, z;
#pragma unroll
        for (int i = 0; i < 8; ++i) { a[i] = 0; z[i] = 0; }
        a[0] = c2h; a[1] = 0x3F80; a[2] = e2c;
        *reinterpret_cast<u16x8*>(hiA + k * AROW + 128) = a;
        *reinterpret_cast<u16x8*>(hiA + k * AROW + 136) = z;
    }
    if (l == 1) {   // lo fold row: {c2l, 0, 0, 1, 0...}
        unsigned short c2h = bf16_bits(c2);
        unsigned short c2l = bf16_bits(c2 - bf16_val(c2h));
        u16x8 a, z;
#pragma unroll
        for (int i = 0; i < 8; ++i) { a[i] = 0; z[i] = 0; }
        a[0] = c2l; a[3] = 0x3F80;
        *reinterpret_cast<u16x8*>(loA + k * AROW + 128) = a;
        *reinterpret_cast<u16x8*>(loA + k * AROW + 136) = z;
    }
    if (l == 2) pack[k] = 0xFFFFFFFFFFFFFFFFULL;
}

__launch_bounds__(512, 2)
__global__ void cluster_mfma(const float* __restrict__ embs,
                             const unsigned short* __restrict__ hiA,
                             const unsigned short* __restrict__ loA,
                             unsigned long long* __restrict__ pack,
                             unsigned* __restrict__ minA,
                             unsigned* __restrict__ minB) {
    __shared__ __align__(16) char lds_c[2 * BUFB + TPB * 32 * 4];
    unsigned* minarr = reinterpret_cast<unsigned*>(lds_c + MINOFF);

    const int t = threadIdx.x, w = t >> 6, l = t & 63;
    const int col = l & 31, half = l >> 5;
    const int kside = blockIdx.x & 1, ngrp = blockIdx.x >> 1;
    const int kbase = kside * 256 + w * 32;
    const int myk = kbase + col;
    const int srow = t >> 4, schunk = t & 15;
    const int tbase = ngrp * TPB;

    // ---- A fragments from precomputed split (9 hi + 9 lo, incl. fold) ----
    bf16x8 a_hi[9], a_lo[9];
    {
        const unsigned short* hrow = hiA + myk * AROW + 8 * half;
        const unsigned short* lrow = loA + myk * AROW + 8 * half;
#pragma unroll
        for (int s = 0; s < 9; ++s) {
            a_hi[s] = *reinterpret_cast<const bf16x8*>(hrow + 16 * s);
            a_lo[s] = *reinterpret_cast<const bf16x8*>(lrow + 16 * s);
        }
    }

    float    best_d[16];
    unsigned best_n[16];
#pragma unroll
    for (int r = 0; r < 16; ++r) { best_d[r] = 3.4e38f; best_n[r] = 0u; }

    if (t < TPB * 32) minarr[t] = 0xFFFFFFFFu;

    // preload tile 0
    float vcur[8];
    {
        const float* erow = embs + (tbase * 32 + srow) * D_DIM + schunk * 8;
        float4 u0 = *reinterpret_cast<const float4*>(erow);
        float4 u1 = *reinterpret_cast<const float4*>(erow + 4);
        vcur[0] = u0.x; vcur[1] = u0.y; vcur[2] = u0.z; vcur[3] = u0.w;
        vcur[4] = u1.x; vcur[5] = u1.y; vcur[6] = u1.z; vcur[7] = u1.w;
    }

    for (int tl = 0; tl < TPB; ++tl) {
        char* buf = lds_c + (tl & 1) * BUFB;

        // ---- prefetch next tile into regs; consumed NEXT iteration, so these
        //      loads may stay in flight across the barrier (no vmcnt drain) ----
        float vnx[8];
        {
            const int tn = (tl < TPB - 1) ? tl + 1 : tl;   // clamped dup on last iter
            const float* erow = embs + ((tbase + tn) * 32 + srow) * D_DIM + schunk * 8;
            float4 u0 = *reinterpret_cast<const float4*>(erow);
            float4 u1 = *reinterpret_cast<const float4*>(erow + 4);
            vnx[0] = u0.x; vnx[1] = u0.y; vnx[2] = u0.z; vnx[3] = u0.w;
            vnx[4] = u1.x; vnx[5] = u1.y; vnx[6] = u1.z; vnx[7] = u1.w;
        }

        // ---- convert current tile -> LDS (hi/lo) + x2 fold rows ----
        {
            float x2p = 0.f;
            u16x8 hv, lv;
#pragma unroll
            for (int i = 0; i < 8; ++i) {
                float v = vcur[i];
                x2p = fmaf(v, v, x2p);
                unsigned short hb = bf16_bits(v);
                unsigned short lb = bf16_bits(v - bf16_val(hb));
                hv[i] = hb; lv[i] = lb;
            }
            const int wb = BLK(schunk, srow);
            *reinterpret_cast<u16x8*>(buf + (wb << 4)) = hv;
            *reinterpret_cast<u16x8*>(buf + LOOFF + (wb << 4)) = lv;
            float x2 = x2p;
#pragma unroll
            for (int off = 1; off < 16; off <<= 1) x2 += __shfl_xor(x2, off);
            if (schunk == 0) {
                unsigned short x2h = bf16_bits(x2);
                float x2hf = bf16_val(x2h);
                unsigned short x2l = bf16_bits(x2 - x2hf);
                float x2lf = bf16_val(x2l);
                unsigned short e2x = bf16_bits(x2 - x2hf - x2lf);
                u16x8 he, le, z;
#pragma unroll
                for (int i = 0; i < 8; ++i) { he[i] = 0; le[i] = 0; z[i] = 0; }
                he[0] = 0x3F80; he[1] = x2h; he[2] = 0x3F80; he[3] = e2x;
                le[1] = x2l;
                const int b16 = BLK(16, srow), b17 = BLK(17, srow);
                *reinterpret_cast<u16x8*>(buf + (b16 << 4)) = he;
                *reinterpret_cast<u16x8*>(buf + (b17 << 4)) = z;
                *reinterpret_cast<u16x8*>(buf + LOOFF + (b16 << 4)) = le;
                *reinterpret_cast<u16x8*>(buf + LOOFF + (b17 << 4)) = z;
            }
        }
        // Raw barrier: only LDS writes must be visible (lgkmcnt). The vnx global
        // loads deliberately remain outstanding (T4: counted-vmcnt-style).
        asm volatile("s_waitcnt lgkmcnt(0)" ::: "memory");
        __builtin_amdgcn_s_barrier();

        // ---- MFMA: 9 steps x 3 passes; acc IS d2 (x2+c2 folded) ----
        f32x16 acc;
#pragma unroll
        for (int r = 0; r < 16; ++r) acc[r] = 0.f;
#pragma unroll
        for (int s = 0; s < 9; ++s) {
            const int gg = (s < 8) ? (2 * s + half) : (16 + half);
            const char* pb = buf + (BLK(gg, col) << 4);
            bf16x8 bh = *reinterpret_cast<const bf16x8*>(pb);
            bf16x8 bl = *reinterpret_cast<const bf16x8*>(pb + LOOFF);
            acc = __builtin_amdgcn_mfma_f32_32x32x16_bf16(a_hi[s], bh, acc, 0, 0, 0);
            acc = __builtin_amdgcn_mfma_f32_32x32x16_bf16(a_hi[s], bl, acc, 0, 0, 0);
            acc = __builtin_amdgcn_mfma_f32_32x32x16_bf16(a_lo[s], bh, acc, 0, 0, 0);
        }

        // ---- epilogue: loss min (per n) + rep running best (per k) ----
        float m = acc[0];
#pragma unroll
        for (int r = 1; r < 16; ++r) m = fminf(m, acc[r]);
        m = fminf(m, __shfl_xor(m, 32));
        if (l < 32) atomicMin(&minarr[tl * 32 + col], __float_as_uint(m));

        const unsigned ng = (unsigned)((tbase + tl) * 32 + col);
#pragma unroll
        for (int r = 0; r < 16; ++r) {
            bool better = acc[r] < best_d[r];
            best_d[r] = better ? acc[r] : best_d[r];
            best_n[r] = better ? ng : best_n[r];
        }

#pragma unroll
        for (int i = 0; i < 8; ++i) vcur[i] = vnx[i];
    }
    __syncthreads();   // full drain once, before cross-wave minarr read

    // ---- per-n mins: plain store per kside (no global atomics) ----
    if (t < TPB * 32) {
        unsigned* dst = kside ? minB : minA;
        dst[ngrp * (TPB * 32) + t] = minarr[t];
    }

    // ---- rep: cross-lane lexicographic argmin, then global packed atomicMin ----
#pragma unroll
    for (int r = 0; r < 16; ++r) {
        float d = best_d[r];
        unsigned n = best_n[r];
        for (int off = 16; off >= 1; off >>= 1) {
            float od = __shfl_xor(d, off);
            unsigned on = __shfl_xor(n, off);
            bool take = (od < d) || (od == d && on < n);
            d = take ? od : d;
            n = take ? on : n;
        }
        if (col == 0) {
            int k = kbase + (r & 3) + 8 * (r >> 2) + 4 * half;
            unsigned long long p =
                ((unsigned long long)__float_as_uint(d) << 32) | (unsigned long long)n;
            atomicMin(&pack[k], p);
        }
    }
}

__global__ void finalize1(const float* __restrict__ centers,
                          const unsigned long long* __restrict__ pack,
                          const unsigned* __restrict__ minA,
                          const unsigned* __restrict__ minB,
                          float* __restrict__ lossPartial,
                          float* __restrict__ out) {
    __shared__ float wsum[8];
    const int t = threadIdx.x, wv = t >> 6, ln = t & 63;
    const int gid = blockIdx.x * 512 + t;
    if (gid < 16384)
        reinterpret_cast<float4*>(out)[gid] =
            reinterpret_cast<const float4*>(centers)[gid];
    if (gid < K_C)
        out[65536 + gid] = (float)(unsigned)(pack[gid] & 0xFFFFFFFFu);
    float s = 0.f;
    if (gid < N_EMB) {
        float m = fminf(__uint_as_float(minA[gid]), __uint_as_float(minB[gid]));
        s = sqrtf(fmaxf(m, 1e-12f));
    }
#pragma unroll
    for (int off = 1; off < 64; off <<= 1) s += __shfl_xor(s, off);
    if (ln == 0) wsum[wv] = s;
    __syncthreads();
    if (t == 0) {
        float tot = 0.f;
#pragma unroll
        for (int i = 0; i < 8; ++i) tot += wsum[i];
        lossPartial[blockIdx.x] = tot;   // plain store — NO global atomics
    }
}

__global__ void finalize2(const float* __restrict__ lossPartial,
                          float* __restrict__ out) {
    __shared__ float wsum[8];
    const int t = threadIdx.x, wv = t >> 6, ln = t & 63;
    float s = (t < 391) ? lossPartial[t] : 0.f;
#pragma unroll
    for (int off = 1; off < 64; off <<= 1) s += __shfl_xor(s, off);
    if (ln == 0) wsum[wv] = s;
    __syncthreads();
    if (t == 0) {
        float tot = 0.f;
#pragma unroll
        for (int i = 0; i < 8; ++i) tot += wsum[i];
        out[65536 + K_C] = tot;
    }
}

extern "C" void kernel_launch(void* const* d_in, const int* in_sizes, int n_in,
                              void* d_out, int out_size, void* d_ws, size_t ws_size,
                              hipStream_t stream) {
    const float* embs    = (const float*)d_in[0];
    const float* centers = (const float*)d_in[1];
    float* out = (float*)d_out;

    unsigned long long* pack = (unsigned long long*)d_ws;
    unsigned short* hiA = (unsigned short*)((char*)d_ws + 4096);
    unsigned short* loA = (unsigned short*)((char*)d_ws + 151552);
    unsigned* minA = (unsigned*)((char*)d_ws + 299008);
    unsigned* minB = (unsigned*)((char*)d_ws + 1099008);
    float* lossPartial = (float*)((char*)d_ws + 1899008);

    init_kernel<<<64, 512, 0, stream>>>(centers, hiA, loA, pack);
    cluster_mfma<<<NGRPS * 2, 512, 0, stream>>>(embs, hiA, loA, pack, minA, minB);
    finalize1<<<391, 512, 0, stream>>>(centers, pack, minA, minB, lossPartial, out);
    finalize2<<<1, 512, 0, stream>>>(lossPartial, out);
}